// Round 9
// baseline (376.169 us; speedup 1.0000x reference)
//
#include <hip/hip_runtime.h>
#include <math.h>

// Problem: bs=8, seq=2048, d_in=d_out=2048, R=8, ctr_out=32, ctr_final=4
// ws layout (floats): A[8*8*2048] | B[8*8*2048]  (B has SCALING folded in)

#define BS 8
#define SEQ 2048
#define DIM 2048
#define RR 8
#define SCALING 2.0f   // 16.0 / R

typedef float vf4 __attribute__((ext_vector_type(4)));

// ---------------------------------------------------------------------------
// Kernel 1: gating MLP + A/B generation. (unchanged — ~6 µs, off critical path)
// ---------------------------------------------------------------------------
__global__ void gate_ab_kernel(const float* __restrict__ ctr,
                               const float* __restrict__ gamma,
                               const float* __restrict__ beta,
                               const float* __restrict__ W1,
                               const float* __restrict__ b1,
                               const float* __restrict__ W2,
                               const float* __restrict__ b2,
                               const float* __restrict__ Wa,
                               const float* __restrict__ Wb,
                               float* __restrict__ A,
                               float* __restrict__ B) {
    __shared__ float z_s[BS][32];
    __shared__ float h_s[BS][60];
    __shared__ float logit_s[BS][4];
    __shared__ float gate_s[BS][4];
    const int tid = threadIdx.x;

    {
        const int b = tid >> 5, i = tid & 31;
        float v = ctr[b * 32 + i];
        float s = v;
        #pragma unroll
        for (int m = 16; m; m >>= 1) s += __shfl_xor(s, m, 64);
        const float mu = s * (1.0f / 32.0f);
        const float d = v - mu;
        float sq = d * d;
        #pragma unroll
        for (int m = 16; m; m >>= 1) sq += __shfl_xor(sq, m, 64);
        const float var = sq * (1.0f / 32.0f);
        z_s[b][i] = d * rsqrtf(var + 1e-5f) * gamma[i] + beta[i];
    }
    __syncthreads();

    for (int idx = tid; idx < BS * 60; idx += 256) {
        const int b = idx / 60, j = idx % 60;
        float acc = b1[j];
        #pragma unroll
        for (int k = 0; k < 32; ++k) acc += z_s[b][k] * W1[j * 32 + k];
        h_s[b][j] = fmaxf(acc, 0.0f);
    }
    __syncthreads();

    if (tid < 32) {
        const int b = tid >> 2, c = tid & 3;
        float acc = b2[c];
        for (int k = 0; k < 60; ++k) acc += h_s[b][k] * W2[c * 60 + k];
        logit_s[b][c] = acc;
    }
    __syncthreads();

    if (tid < 8) {
        float m = logit_s[tid][0];
        #pragma unroll
        for (int c = 1; c < 4; ++c) m = fmaxf(m, logit_s[tid][c]);
        float e[4], s = 0.0f;
        #pragma unroll
        for (int c = 0; c < 4; ++c) { e[c] = expf(logit_s[tid][c] - m); s += e[c]; }
        const float inv = 1.0f / s;
        #pragma unroll
        for (int c = 0; c < 4; ++c) gate_s[tid][c] = e[c] * inv;
    }
    __syncthreads();

    const vf4* __restrict__ Wa4 = (const vf4*)Wa;
    const vf4* __restrict__ Wb4 = (const vf4*)Wb;
    const int total = BS * RR * DIM;   // 131072
    for (int idx = blockIdx.x * 256 + tid; idx < total; idx += gridDim.x * 256) {
        const int b = idx >> 14, rd = idx & 16383;
        const vf4 g = *(const vf4*)gate_s[b];
        const vf4 wa = Wa4[rd];
        A[idx] = g.x * wa.x + g.y * wa.y + g.z * wa.z + g.w * wa.w;
        const vf4 wb = Wb4[rd];
        B[idx] = SCALING * (g.x * wb.x + g.y * wb.y + g.z * wb.z + g.w * wb.w);
    }
}

// ---------------------------------------------------------------------------
// Fused kernel v6 — high-occupancy, spill-proof, L2-operand, zero-barrier.
// EVIDENCE LOG (9 measurements):
//  - v1 & r8 (LDS-staged, no spill): BOTH traffic-clean and BOTH exactly
//    83-84 us at 2.46 TB/s. Barriers vs none changed NOTHING -> phase
//    serialization was never the limit.
//  - ALL dirty-traffic kernels (r1/r5/r6/r7) had live-regs > VGPR_Count:
//    dirt was scratch SPILL, not store RMW. No-spill => clean, always.
//  - m13 float4 COPY (read+write mixed) does 6.29 TB/s at 32 waves/CU.
//    r8: 8 waves/CU (128KB LDS -> 1 block/CU), Occupancy 17%, VALUBusy 15%
//    => latency-bound from low occupancy + issue gaps. LDS is the cap.
// DESIGN: no LDS at all. A/B (1 MB total) are L2-hot (replicated per XCD).
//  - 2 rows/wave, 4 waves/block, 2048 blocks, ZERO barriers.
//  - live regs ~75 (acc 16 + xcur/xnxt 16 + a4 32 + addr) -> no spill at
//    the __launch_bounds__(256,5) cap (~102 VGPR) -> ~20 waves/CU.
//  - L2 re-read: 128 KB per 2 rows = 1.0 GB aggregate = ~23 TB/s at 45 us,
//    under the 34.5 TB/s L2 ceiling (2.9/4.3 TB/s per XCD; ~91/153 GB/s L1).
// ---------------------------------------------------------------------------
__global__ void __launch_bounds__(256, 5)
fused_kernel(const float* __restrict__ x, const float* __restrict__ A,
             const float* __restrict__ B, float* __restrict__ out) {
    const int b    = blockIdx.x >> 8;     // 256 blocks per sample
    const int tile = blockIdx.x & 255;    // 8 rows per block
    const int wave = threadIdx.x >> 6, lane = threadIdx.x & 63;
    const int row0 = tile * 8 + wave * 2;
    const int l4   = lane * 4;

    const float* __restrict__ xr = x + ((size_t)(b * SEQ + row0)) * DIM;
    const float* __restrict__ Ab = A + b * (RR * DIM);
    const float* __restrict__ Bb = B + b * (RR * DIM);

    float acc[2][8];
    #pragma unroll
    for (int i = 0; i < 2; ++i)
        #pragma unroll
        for (int r = 0; r < 8; ++r) acc[i][r] = 0.0f;

    // ---- phase 1: xa = x . A^T (2 rows/wave), x pipelined 1 deep ----
    float4 xcur[2], xnxt[2];
    xcur[0] = *(const float4*)&xr[l4];
    xcur[1] = *(const float4*)&xr[DIM + l4];
    #pragma unroll
    for (int j = 0; j < 8; ++j) {
        const int d = j * 256 + l4;
        if (j < 7) {
            xnxt[0] = *(const float4*)&xr[d + 256];
            xnxt[1] = *(const float4*)&xr[DIM + d + 256];
        }
        float4 a4[8];
        #pragma unroll
        for (int r = 0; r < 8; ++r) a4[r] = *(const float4*)&Ab[r * DIM + d];
        #pragma unroll
        for (int r = 0; r < 8; ++r) {
            acc[0][r] += xcur[0].x * a4[r].x + xcur[0].y * a4[r].y +
                         xcur[0].z * a4[r].z + xcur[0].w * a4[r].w;
            acc[1][r] += xcur[1].x * a4[r].x + xcur[1].y * a4[r].y +
                         xcur[1].z * a4[r].z + xcur[1].w * a4[r].w;
        }
        xcur[0] = xnxt[0];
        xcur[1] = xnxt[1];
    }

    // butterfly reduce across 64 lanes -> every lane holds xa[i][r]
    float xa[2][8];
    #pragma unroll
    for (int i = 0; i < 2; ++i) {
        #pragma unroll
        for (int r = 0; r < 8; ++r) {
            float v = acc[i][r];
            #pragma unroll
            for (int off = 32; off; off >>= 1) v += __shfl_xor(v, off, 64);
            xa[i][r] = v;
        }
    }

    // ---- phase 2: out = xa . B, B from L2, plain float4 stores ----
    float* __restrict__ ob = out + ((size_t)(b * SEQ + row0)) * DIM;
    #pragma unroll
    for (int j = 0; j < 8; ++j) {
        const int o = j * 256 + l4;
        float4 b4[8];
        #pragma unroll
        for (int r = 0; r < 8; ++r) b4[r] = *(const float4*)&Bb[r * DIM + o];
        float4 o0 = {0.0f, 0.0f, 0.0f, 0.0f};
        float4 o1 = {0.0f, 0.0f, 0.0f, 0.0f};
        #pragma unroll
        for (int r = 0; r < 8; ++r) {
            o0.x += xa[0][r] * b4[r].x; o0.y += xa[0][r] * b4[r].y;
            o0.z += xa[0][r] * b4[r].z; o0.w += xa[0][r] * b4[r].w;
            o1.x += xa[1][r] * b4[r].x; o1.y += xa[1][r] * b4[r].y;
            o1.z += xa[1][r] * b4[r].z; o1.w += xa[1][r] * b4[r].w;
        }
        *(float4*)&ob[o] = o0;
        *(float4*)&ob[DIM + o] = o1;
    }
}

extern "C" void kernel_launch(void* const* d_in, const int* in_sizes, int n_in,
                              void* d_out, int out_size, void* d_ws, size_t ws_size,
                              hipStream_t stream) {
    const float* x     = (const float*)d_in[0];
    const float* ctr   = (const float*)d_in[1];
    const float* gamma = (const float*)d_in[2];
    const float* beta  = (const float*)d_in[3];
    const float* W1    = (const float*)d_in[4];
    const float* b1    = (const float*)d_in[5];
    const float* W2    = (const float*)d_in[6];
    const float* b2    = (const float*)d_in[7];
    const float* Wa    = (const float*)d_in[8];
    const float* Wb    = (const float*)d_in[9];

    float* ws = (float*)d_ws;
    float* A  = ws;                  // 131072 floats
    float* B  = ws + 131072;         // 131072 floats
    float* out = (float*)d_out;

    gate_ab_kernel<<<128, 256, 0, stream>>>(ctr, gamma, beta, W1, b1, W2, b2,
                                            Wa, Wb, A, B);
    fused_kernel<<<BS * 256, 256, 0, stream>>>(x, A, B, out);
}